// Round 11
// baseline (280.837 us; speedup 1.0000x reference)
//
#include <hip/hip_runtime.h>
#include <hip/hip_bf16.h>

#define NB 8
#define NC 192
#define NH 48
#define NW 48
#define NP 2304        // 48*48
#define NGROUPS 32
#define CPG 6          // NC/NGROUPS
#define NEMB 192
#define NCQ 16

// padded-transposed activation: [B][50 h'][52 w' stride (50 used)][192 c] bf16
#define PH 50
#define PWS 52
#define ACT_T_ELEMS ((size_t)NB * PH * PWS * NC)   // 3,993,600 bf16
#define AOT_ELEMS   ((size_t)NB * PH * PWS * 16)   // 332,800 bf16

typedef __attribute__((ext_vector_type(4))) short s16x4;
typedef __attribute__((ext_vector_type(8))) short s16x8;
typedef __attribute__((ext_vector_type(4))) float f32x4;

static __device__ inline short f2bf(float v) {
  __hip_bfloat16 h = __float2bfloat16(v);
  return *(short*)&h;
}

// ---------------- FRONT: weight reorders + affine + halos + gn1 stats + zeroB ----------
// ranges: [0,1296) wprep1 | [1296,2592) wprep2 | [2592,2808) wprep_o | [2808,2820) awq |
// [2820,2844) awkv | [2844,2850) affine | [2850,3154) actt halo | [3154,3162) aot halo |
// [3162,4698) gn1 stats partials (256 bg x 6 seg) | [4698] zero gnpartB
__global__ __launch_bounds__(256) void front_kernel(
    const float* __restrict__ conv1w, const float* __restrict__ conv2w,
    const float* __restrict__ outw, const float* __restrict__ qw,
    const float* __restrict__ kvw, const float* __restrict__ emb,
    const float* __restrict__ affw, const float* __restrict__ affb,
    const float* __restrict__ x,
    short* __restrict__ wbuf1, short* __restrict__ wbuf2, short* __restrict__ wbufo,
    short* __restrict__ awq, short* __restrict__ awkv,
    float* __restrict__ gbsum, short* __restrict__ actt, short* __restrict__ aot,
    float* __restrict__ gnpartA, float* __restrict__ gnpartB) {
  __shared__ float red[8];
  int bx = blockIdx.x;
  int tid = threadIdx.x;
  const float SC = 0.36067376022224085f;  // 0.25 * log2(e)
  if (bx < 2592) {
    const float* w = (bx < 1296) ? conv1w : conv2w;
    short* wb      = (bx < 1296) ? wbuf1 : wbuf2;
    int i = ((bx < 1296) ? bx : bx - 1296) * 256 + tid;
    int j  = i & 7;
    int l  = (i >> 3) & 63;
    int cf = (i >> 9) % 12;
    int tk = (i >> 9) / 12;
    int t  = tk % 9;
    int kc = tk / 9;
    int co = cf * 16 + (l & 15);
    int ci = kc * 32 + (l >> 4) * 8 + j;
    wb[i] = f2bf(w[((size_t)co * NC + ci) * 9 + t]);
  } else if (bx < 2808) {
    int i = (bx - 2592) * 256 + tid;
    int j  = i & 7;
    int l  = (i >> 3) & 63;
    int cf = (i >> 9) % 12;
    int t  = (i >> 9) / 12;
    int co = cf * 16 + (l & 15);
    int ci = (l >> 4) * 8 + j;
    wbufo[i] = (ci < 16) ? f2bf(outw[((size_t)co * 16 + ci) * 9 + t]) : (short)0;
  } else if (bx < 2820) {
    int i = (bx - 2808) * 256 + tid;
    int j = i & 7, l = (i >> 3) & 63, kc = i >> 9;
    int co = (l & 15);
    int ci = kc * 32 + (l >> 4) * 8 + j;
    awq[i] = f2bf(qw[(size_t)co * NC + ci] * SC);
  } else if (bx < 2844) {
    int i = (bx - 2820) * 256 + tid;
    int j = i & 7, l = (i >> 3) & 63, rest = i >> 9;
    int m = rest % 2, kc = rest / 2;
    int co = m * 16 + (l & 15);
    int ci = kc * 32 + (l >> 4) * 8 + j;
    awkv[i] = f2bf(kvw[(size_t)co * NC + ci]);
  } else if (bx < 2850) {
    int i = (bx - 2844) * 256 + tid;
    if (i < NB * NC) {
      int b = i / NC;
      int c = i - b * NC;
      const float* e  = emb + b * NEMB;
      const float* w0 = affw + c * NEMB;
      const float* w1 = affw + (c + NC) * NEMB;
      float s = 0.f;
      for (int j = 0; j < NEMB; ++j) s += e[j] * (w0[j] + w1[j]);
      gbsum[i] = 0.5f * (s + affb[c] + affb[c + NC]);
    }
  } else if (bx < 3154) {
    int rel = bx - 2850;
    int b = rel / 38, xb = rel - b * 38;
    int i = xb * 256 + tid;
    if (i < 9600) {
      int c4 = i % 48;
      int r  = i / 48;
      size_t off;
      if (r < 52)       off = ((size_t)0 * PWS + r) * NC;
      else if (r < 104) off = ((size_t)49 * PWS + (r - 52)) * NC;
      else if (r < 152) off = ((size_t)(r - 104 + 1) * PWS + 0) * NC;
      else              off = ((size_t)(r - 152 + 1) * PWS + 49) * NC;
      *(s16x4*)(&actt[(size_t)b * PH * PWS * NC + off + c4 * 4]) = (s16x4){0, 0, 0, 0};
    }
  } else if (bx < 3162) {
    int b = bx - 3154;
    for (int i = tid; i < 784; i += 256) {
      int c4  = i & 3;
      int pos = i >> 2;
      int r, col;
      if (pos < 50)       { r = 0;  col = pos; }
      else if (pos < 100) { r = 49; col = pos - 50; }
      else if (pos < 148) { r = pos - 100 + 1; col = 0; }
      else                { r = pos - 148 + 1; col = 49; }
      *(s16x4*)(&aot[(((size_t)b * PH + r) * PWS + col) * 16 + c4 * 4]) = (s16x4){0, 0, 0, 0};
    }
  } else if (bx < 4698) {                 // gn1 stats partials on x
    int rel = bx - 3162;
    int bg = rel / 6, seg = rel - bg * 6;
    const float4* p = (const float4*)(x + (size_t)bg * (CPG * NP) + seg * 2304);
    float s = 0.f, s2 = 0.f;
    for (int i = tid; i < 576; i += 256) {
      float4 v = p[i];
      s  += v.x + v.y + v.z + v.w;
      s2 += v.x * v.x + v.y * v.y + v.z * v.z + v.w * v.w;
    }
#pragma unroll
    for (int off = 32; off > 0; off >>= 1) {
      s  += __shfl_down(s, off);
      s2 += __shfl_down(s2, off);
    }
    int wave = tid >> 6;
    if ((tid & 63) == 0) { red[wave * 2] = s; red[wave * 2 + 1] = s2; }
    __syncthreads();
    if (tid == 0) {
      gnpartA[(bg * 6 + seg) * 2]     = red[0] + red[2] + red[4] + red[6];
      gnpartA[(bg * 6 + seg) * 2 + 1] = red[1] + red[3] + red[5] + red[7];
    }
  } else {                                // zero gnpartB (512 floats)
    gnpartB[tid] = 0.f;
    gnpartB[tid + 256] = 0.f;
  }
}

// ---------------- MID1: kv-projection(xe) [0,384) + gn1-apply(x) [384,768) ----------
__global__ __launch_bounds__(256) void mid1_kernel(
    const float* __restrict__ xe, const short* __restrict__ awkv,
    short* __restrict__ Kb, short* __restrict__ VTb,
    const float* __restrict__ x, const float* __restrict__ gnpartA,
    const float* __restrict__ gw, const float* __restrict__ gb,
    short* __restrict__ actt) {
  __shared__ float tile[48 * 193];
  __shared__ float sst[32][2];
  int bx = blockIdx.x;
  int tid = threadIdx.x;
  if (bx < 384) {
    // ---- kv projection: xe -> Kb[p][32] (pad), VTb[16][p]
    int b = bx / NH, h = bx - (bx / NH) * NH;
    for (int i = tid; i < 2304; i += 256) {
      int c = i / 12;
      int w = (i % 12) * 4;
      float4 v = *(const float4*)(xe + (((size_t)b * NC + c) * NH + h) * NW + w);
      tile[(w + 0) * 193 + c] = v.x;
      tile[(w + 1) * 193 + c] = v.y;
      tile[(w + 2) * 193 + c] = v.z;
      tile[(w + 3) * 193 + c] = v.w;
    }
    __syncthreads();
    int lane = tid & 63, wv = tid >> 6;
    if (wv < 3) {
      int g = lane >> 4, ql = lane & 15;
      int pxl = wv * 16 + ql;
      int p = h * NW + pxl;
      f32x4 acc0 = {0.f, 0.f, 0.f, 0.f}, acc1 = {0.f, 0.f, 0.f, 0.f};
      const float* bp = &tile[pxl * 193 + g * 8];
#pragma unroll
      for (int kc = 0; kc < 6; ++kc) {
        s16x8 bf;
#pragma unroll
        for (int j = 0; j < 8; ++j) bf[j] = f2bf(bp[kc * 32 + j]);
        s16x8 a0 = *(const s16x8*)(awkv + ((size_t)(kc * 2 + 0) * 64 + lane) * 8);
        s16x8 a1 = *(const s16x8*)(awkv + ((size_t)(kc * 2 + 1) * 64 + lane) * 8);
        acc0 = __builtin_amdgcn_mfma_f32_16x16x32_bf16(a0, bf, acc0, 0, 0, 0);
        acc1 = __builtin_amdgcn_mfma_f32_16x16x32_bf16(a1, bf, acc1, 0, 0, 0);
      }
      s16x4 o0;
      o0.x = f2bf(acc0[0]); o0.y = f2bf(acc0[1]);
      o0.z = f2bf(acc0[2]); o0.w = f2bf(acc0[3]);
      *(s16x4*)(Kb + ((size_t)b * NP + p) * 32 + g * 4) = o0;
      *(s16x4*)(Kb + ((size_t)b * NP + p) * 32 + 16 + g * 4) = (s16x4){0, 0, 0, 0};
#pragma unroll
      for (int r = 0; r < 4; ++r)
        VTb[((size_t)b * 16 + g * 4 + r) * NP + p] = f2bf(acc1[r]);
    }
  } else {
    // ---- gn1 apply + swish -> actt (stats from segmented gnpartA)
    int bh = bx - 384;
    int b = bh / NH, h = bh - (bh / NH) * NH;
    if (tid < 32) {
      float S = 0.f, S2 = 0.f;
#pragma unroll
      for (int k = 0; k < 6; ++k) {
        S  += gnpartA[((b * 32 + tid) * 6 + k) * 2];
        S2 += gnpartA[((b * 32 + tid) * 6 + k) * 2 + 1];
      }
      const float invN = 1.f / (float)(CPG * NP);
      float mean = S * invN;
      float var  = S2 * invN - mean * mean;
      sst[tid][0] = mean;
      sst[tid][1] = rsqrtf(var + 1e-5f);
    }
    __syncthreads();
    for (int i = tid; i < 2304; i += 256) {
      int c = i / 12;
      int w = (i % 12) * 4;
      float4 v = *(const float4*)(x + (((size_t)b * NC + c) * NH + h) * NW + w);
      float sc = sst[c / CPG][1] * gw[c];
      float sh = gb[c] - sst[c / CPG][0] * sc;
      float y;
      y = v.x * sc + sh; tile[(w + 0) * 193 + c] = y / (1.f + __expf(-y));
      y = v.y * sc + sh; tile[(w + 1) * 193 + c] = y / (1.f + __expf(-y));
      y = v.z * sc + sh; tile[(w + 2) * 193 + c] = y / (1.f + __expf(-y));
      y = v.w * sc + sh; tile[(w + 3) * 193 + c] = y / (1.f + __expf(-y));
    }
    __syncthreads();
    short* dst = actt + (((size_t)b * PH + h + 1) * PWS + 1) * NC;
    for (int i = tid; i < 2304; i += 256) {
      int w  = i / 48;
      int c4 = (i - w * 48) * 4;
      s16x4 o;
      o.x = f2bf(tile[w * 193 + c4 + 0]);
      o.y = f2bf(tile[w * 193 + c4 + 1]);
      o.z = f2bf(tile[w * 193 + c4 + 2]);
      o.w = f2bf(tile[w * 193 + c4 + 3]);
      *(s16x4*)(dst + (size_t)w * NC + c4) = o;
    }
  }
}

// ---------------- gn2 apply (raw totals from gnpartB) -> actt ----------------
__global__ __launch_bounds__(256) void gn_apply_raw_kernel(const float* __restrict__ in,
                                                           const float* __restrict__ gnpartB,
                                                           const float* __restrict__ gw,
                                                           const float* __restrict__ gb,
                                                           short* __restrict__ actt) {
  __shared__ float tile[48 * 193];
  __shared__ float sst[32][2];
  int bh = blockIdx.x;
  int b = bh / NH;
  int h = bh - b * NH;
  int tid = threadIdx.x;
  if (tid < 32) {
    float S  = gnpartB[(b * 32 + tid) * 2];
    float S2 = gnpartB[(b * 32 + tid) * 2 + 1];
    const float invN = 1.f / (float)(CPG * NP);
    float mean = S * invN;
    float var  = S2 * invN - mean * mean;
    sst[tid][0] = mean;
    sst[tid][1] = rsqrtf(var + 1e-5f);
  }
  __syncthreads();
  for (int i = tid; i < 2304; i += 256) {
    int c = i / 12;
    int w = (i % 12) * 4;
    float4 v = *(const float4*)(in + (((size_t)b * NC + c) * NH + h) * NW + w);
    float sc = sst[c / CPG][1] * gw[c];
    float sh = gb[c] - sst[c / CPG][0] * sc;
    float y;
    y = v.x * sc + sh; tile[(w + 0) * 193 + c] = y / (1.f + __expf(-y));
    y = v.y * sc + sh; tile[(w + 1) * 193 + c] = y / (1.f + __expf(-y));
    y = v.z * sc + sh; tile[(w + 2) * 193 + c] = y / (1.f + __expf(-y));
    y = v.w * sc + sh; tile[(w + 3) * 193 + c] = y / (1.f + __expf(-y));
  }
  __syncthreads();
  short* dst = actt + (((size_t)b * PH + h + 1) * PWS + 1) * NC;
  for (int i = tid; i < 2304; i += 256) {
    int w  = i / 48;
    int c4 = (i - w * 48) * 4;
    s16x4 o;
    o.x = f2bf(tile[w * 193 + c4 + 0]);
    o.y = f2bf(tile[w * 193 + c4 + 1]);
    o.z = f2bf(tile[w * 193 + c4 + 2]);
    o.w = f2bf(tile[w * 193 + c4 + 3]);
    *(s16x4*)(dst + (size_t)w * NC + c4) = o;
  }
}

// ---------------- conv3x3 via MFMA, CI=192, dbuf; optional fused gn-stats epilogue -----
template <bool AFFINE, bool RESID, bool STATS>
__global__ __launch_bounds__(256) void conv_mfma_kernel(const short* __restrict__ actt,
                                                        const short* __restrict__ wbuf,
                                                        const float* __restrict__ bias,
                                                        const float* __restrict__ gbsum,
                                                        const float* __restrict__ resid,
                                                        float* __restrict__ out,
                                                        float* __restrict__ gnpartB) {
  __shared__ short S[2][4][50][40];       // 32 KB double buffer
  __shared__ float csum[64][2];
  int bs = blockIdx.x;
  int b = bs / 24;
  int strip = bs - b * 24;
  int coB = blockIdx.y;
  int h0 = strip * 2;
  int tid = threadIdx.x;
  int lane = tid & 63, wave = tid >> 6;
  int wy = wave >> 1, wx = wave & 1;
  int g8 = (lane >> 4) * 8;

  if (STATS && tid < 64) { csum[tid][0] = 0.f; csum[tid][1] = 0.f; }

  f32x4 acc[2][3];
#pragma unroll
  for (int m = 0; m < 2; ++m)
#pragma unroll
    for (int f = 0; f < 3; ++f) acc[m][f] = (f32x4){0.f, 0.f, 0.f, 0.f};

  const size_t actbase = ((size_t)b * PH + h0) * PWS * NC;

  auto stage = [&](int buf, int kc) {
    for (int i = tid; i < 800; i += 256) {
      int ci8 = i & 3;
      int rc  = i >> 2;
      int col = rc % 50, r = rc / 50;
      const s16x8* src = (const s16x8*)(actt + actbase + ((size_t)r * PWS + col) * NC +
                                        kc * 32 + ci8 * 8);
      *(s16x8*)(&S[buf][r][col][ci8 * 8]) = *src;
    }
  };

  stage(0, 0);
  __syncthreads();
  for (int kc = 0; kc < 6; ++kc) {
    if (kc < 5) stage((kc + 1) & 1, kc + 1);
    int cur = kc & 1;
#pragma unroll
    for (int t = 0; t < 9; ++t) {
      int ky = t / 3, kx = t - ky * 3;
      const short* wp = wbuf + ((((size_t)kc * 9 + t) * 12 + (coB * 4 + wy * 2)) * 64 + lane) * 8;
      s16x8 a0 = *(const s16x8*)wp;
      s16x8 a1 = *(const s16x8*)(wp + 64 * 8);
      int row = wx + ky;
#pragma unroll
      for (int f = 0; f < 3; ++f) {
        int col = f * 16 + (lane & 15) + kx;
        s16x8 bf = *(const s16x8*)(&S[cur][row][col][g8]);
        acc[0][f] = __builtin_amdgcn_mfma_f32_16x16x32_bf16(a0, bf, acc[0][f], 0, 0, 0);
        acc[1][f] = __builtin_amdgcn_mfma_f32_16x16x32_bf16(a1, bf, acc[1][f], 0, 0, 0);
      }
    }
    __syncthreads();
  }
  int hout = h0 + wx;
#pragma unroll
  for (int m = 0; m < 2; ++m) {
    int co0 = coB * 64 + wy * 32 + m * 16;
#pragma unroll
    for (int r = 0; r < 4; ++r) {
      int co = co0 + (lane >> 4) * 4 + r;
      float bv = bias[co];
      float s = AFFINE ? gbsum[b * NC + co] : 0.f;
      float ls = 0.f, ls2 = 0.f;
#pragma unroll
      for (int f = 0; f < 3; ++f) {
        int w = f * 16 + (lane & 15);
        size_t o = (((size_t)b * NC + co) * NH + hout) * NW + w;
        float v = acc[m][f][r] + bv;
        if (AFFINE) v = v * (1.f + s) + s;
        if (RESID) v += resid[o];
        out[o] = v;
        if (STATS) { ls += v; ls2 += v * v; }
      }
      if (STATS) {
        // sum over the 16 w-lanes of this (co, row) slice
#pragma unroll
        for (int off = 1; off < 16; off <<= 1) {
          ls  += __shfl_xor(ls, off, 64);
          ls2 += __shfl_xor(ls2, off, 64);
        }
        if ((lane & 15) == 0) {
          int lc = wy * 32 + m * 16 + (lane >> 4) * 4 + r;
          atomicAdd(&csum[lc][0], ls);
          atomicAdd(&csum[lc][1], ls2);
        }
      }
    }
  }
  if (STATS) {
    __syncthreads();
    if (tid < 64) {
      int co = coB * 64 + tid;
      int g = co / CPG;
      atomicAdd(&gnpartB[(b * NGROUPS + g) * 2], csum[tid][0]);
      atomicAdd(&gnpartB[(b * NGROUPS + g) * 2 + 1], csum[tid][1]);
    }
  }
}

// ---------------- out conv 3x3 via MFMA, CI=16 (zero-padded to 32), in-place resid ----
__global__ __launch_bounds__(256) void out_conv_mfma_kernel(const short* __restrict__ aot,
                                                            const short* __restrict__ wbuf,
                                                            const float* __restrict__ bias,
                                                            float* __restrict__ out) {
  __shared__ short S[4][50][40];
  int bs = blockIdx.x;
  int b = bs / 24;
  int strip = bs - b * 24;
  int coB = blockIdx.y;
  int h0 = strip * 2;
  int tid = threadIdx.x;
  int lane = tid & 63, wave = tid >> 6;
  int wy = wave >> 1, wx = wave & 1;
  int g8 = (lane >> 4) * 8;

  f32x4 acc[2][3];
#pragma unroll
  for (int m = 0; m < 2; ++m)
#pragma unroll
    for (int f = 0; f < 3; ++f) acc[m][f] = (f32x4){0.f, 0.f, 0.f, 0.f};

  const size_t base = ((size_t)b * PH + h0) * PWS * 16;
  for (int i = tid; i < 800; i += 256) {
    int ci8 = i & 3;
    int rc  = i >> 2;
    int col = rc % 50, r = rc / 50;
    s16x8 v = (s16x8){0, 0, 0, 0, 0, 0, 0, 0};
    if (ci8 < 2)
      v = *(const s16x8*)(aot + base + ((size_t)r * PWS + col) * 16 + ci8 * 8);
    *(s16x8*)(&S[r][col][ci8 * 8]) = v;
  }
  __syncthreads();
#pragma unroll
  for (int t = 0; t < 9; ++t) {
    int ky = t / 3, kx = t - ky * 3;
    const short* wp = wbuf + (((size_t)t * 12 + (coB * 4 + wy * 2)) * 64 + lane) * 8;
    s16x8 a0 = *(const s16x8*)wp;
    s16x8 a1 = *(const s16x8*)(wp + 64 * 8);
    int row = wx + ky;
#pragma unroll
    for (int f = 0; f < 3; ++f) {
      int col = f * 16 + (lane & 15) + kx;
      s16x8 bf = *(const s16x8*)(&S[row][col][g8]);
      acc[0][f] = __builtin_amdgcn_mfma_f32_16x16x32_bf16(a0, bf, acc[0][f], 0, 0, 0);
      acc[1][f] = __builtin_amdgcn_mfma_f32_16x16x32_bf16(a1, bf, acc[1][f], 0, 0, 0);
    }
  }
  int hout = h0 + wx;
#pragma unroll
  for (int m = 0; m < 2; ++m) {
    int co0 = coB * 64 + wy * 32 + m * 16;
#pragma unroll
    for (int r = 0; r < 4; ++r) {
      int co = co0 + (lane >> 4) * 4 + r;
      float bv = bias[co];
#pragma unroll
      for (int f = 0; f < 3; ++f) {
        int w = f * 16 + (lane & 15);
        size_t o = (((size_t)b * NC + co) * NH + hout) * NW + w;
        out[o] = acc[m][f][r] + bv + out[o];
      }
    }
  }
}

// ---------------- MFMA flash attention, KS=4 + defer-max + inline q-projection --------
// grid (36, NB), 1024 thr = 16 waves (qg x ks). Phase 0: stage xres[192][64p] -> LDS;
// each wave projects its own 16 queries via MFMA (+LDS relayout to qfrag). The f32 tile
// region is reused after the main loop for the ks-merge buffers.
__global__ __launch_bounds__(1024) void attn_mfma_kernel(const float* __restrict__ xres,
                                                         const short* __restrict__ awq,
                                                         const short* __restrict__ Kb,
                                                         const short* __restrict__ VTb,
                                                         short* __restrict__ aot) {
  __shared__ float tile[64 * 193];        // 49.4 KB; reused for merge buffers
  __shared__ short QL[16][16][32];        // 16 KB: per-wave Q frags (d padded to 32)
  float (*PM)[4][64] = (float(*)[4][64])tile;
  float (*PL)[4][64] = (float(*)[4][64])(tile + 1024);
  f32x4 (*PA)[4][64] = (f32x4(*)[4][64])(tile + 2048);

  int b    = blockIdx.y;
  int tid  = threadIdx.x;
  int lane = tid & 63;
  int w    = tid >> 6;
  int qg   = w & 3, ks = w >> 2;
  int p0   = blockIdx.x * 64;
  int q0   = p0 + qg * 16;
  int g    = lane >> 4;
  int ql   = lane & 15;

  // phase 0: stage xres[c][p0..p0+63] -> tile[pl][c]  (coalesced along pl)
  for (int i = tid; i < 12288; i += 1024) {
    int c = i >> 6, pl = i & 63;
    tile[pl * 193 + c] = xres[((size_t)b * NC + c) * NP + p0 + pl];
  }
  __syncthreads();
  // q-projection: this wave's 16 queries (ks-redundant, trivial cost)
  {
    f32x4 qa = {0.f, 0.f, 0.f, 0.f};
    const float* bp = &tile[(qg * 16 + ql) * 193 + g * 8];
#pragma unroll
    for (int kc = 0; kc < 6; ++kc) {
      s16x8 bf;
#pragma unroll
      for (int j = 0; j < 8; ++j) bf[j] = f2bf(bp[kc * 32 + j]);
      s16x8 af = *(const s16x8*)(awq + ((size_t)(kc * 64 + lane)) * 8);
      qa = __builtin_amdgcn_mfma_f32_16x16x32_bf16(af, bf, qa, 0, 0, 0);
    }
    // D layout: col=lane&15 = q, row=(lane>>4)*4+r = d  -> QL[q][d]
    s16x4 qv;
    qv.x = f2bf(qa[0]); qv.y = f2bf(qa[1]); qv.z = f2bf(qa[2]); qv.w = f2bf(qa[3]);
    *(s16x4*)&QL[w][ql][g * 4] = qv;
    *(s16x4*)&QL[w][ql][16 + g * 4] = (s16x4){0, 0, 0, 0};
  }
  __syncthreads();   // tile reads done (union with PM/PL/PA), QL complete
  s16x8 qfrag = *(const s16x8*)&QL[w][ql][g * 8];

  int r0 = 8 * (ql >> 2) + (ql & 3);
  const short* Kbase = Kb + (size_t)b * NP * 32 + g * 8;
  const short* Vbase = VTb + ((size_t)b * 16 + ql) * NP;

  f32x4 acc = {0.f, 0.f, 0.f, 0.f};
  float m = -1e30f, l = 0.f;

  int kk = ks * 576;
  s16x8 kf0 = *(const s16x8*)(Kbase + (size_t)(kk + r0) * 32);
  s16x8 kf1 = *(const s16x8*)(Kbase + (size_t)(kk + r0 + 4) * 32);
  s16x8 vf  = *(const s16x8*)(Vbase + kk + g * 8);

  for (int step = 0; step < 18; ++step) {
    int kn = (step < 17) ? kk + 32 : ks * 576;
    s16x8 nk0 = *(const s16x8*)(Kbase + (size_t)(kn + r0) * 32);
    s16x8 nk1 = *(const s16x8*)(Kbase + (size_t)(kn + r0 + 4) * 32);
    s16x8 nv  = *(const s16x8*)(Vbase + kn + g * 8);

    f32x4 z = {0.f, 0.f, 0.f, 0.f};
    f32x4 s0 = __builtin_amdgcn_mfma_f32_16x16x32_bf16(kf0, qfrag, z, 0, 0, 0);
    f32x4 s1 = __builtin_amdgcn_mfma_f32_16x16x32_bf16(kf1, qfrag, z, 0, 0, 0);

    float tm = fmaxf(fmaxf(fmaxf(s0[0], s0[1]), fmaxf(s0[2], s0[3])),
                     fmaxf(fmaxf(s1[0], s1[1]), fmaxf(s1[2], s1[3])));
    if (!__all(tm <= m + 8.0f)) {
      tm = fmaxf(tm, __shfl_xor(tm, 16, 64));
      tm = fmaxf(tm, __shfl_xor(tm, 32, 64));
      float mn = fmaxf(m, tm);
      float corr = exp2f(m - mn);
      m = mn;
      l *= corr;
      acc[0] *= corr; acc[1] *= corr; acc[2] *= corr; acc[3] *= corr;
    }
    float p0e = exp2f(s0[0] - m), p1e = exp2f(s0[1] - m);
    float p2e = exp2f(s0[2] - m), p3e = exp2f(s0[3] - m);
    float p4e = exp2f(s1[0] - m), p5e = exp2f(s1[1] - m);
    float p6e = exp2f(s1[2] - m), p7e = exp2f(s1[3] - m);
    l += ((p0e + p1e) + (p2e + p3e)) + ((p4e + p5e) + (p6e + p7e));

    s16x8 pf;
    pf[0] = f2bf(p0e); pf[1] = f2bf(p1e); pf[2] = f2bf(p2e); pf[3] = f2bf(p3e);
    pf[4] = f2bf(p4e); pf[5] = f2bf(p5e); pf[6] = f2bf(p6e); pf[7] = f2bf(p7e);
    acc = __builtin_amdgcn_mfma_f32_16x16x32_bf16(vf, pf, acc, 0, 0, 0);

    kf0 = nk0; kf1 = nk1; vf = nv; kk = kn;
  }
  PM[ks][qg][lane] = m;
  PL[ks][qg][lane] = l;
  PA[ks][qg][lane] = acc;
  __syncthreads();
  if (ks == 0) {
    float M = PM[0][qg][lane];
#pragma unroll
    for (int k = 1; k < 4; ++k) M = fmaxf(M, PM[k][qg][lane]);
    float L = 0.f;
    f32x4 o = {0.f, 0.f, 0.f, 0.f};
#pragma unroll
    for (int k = 0; k < 4; ++k) {
      float c = exp2f(PM[k][qg][lane] - M);
      L += PL[k][qg][lane] * c;
      f32x4 a = PA[k][qg][lane];
      o[0] += a[0] * c; o[1] += a[1] * c; o[2] += a[2] * c; o[3] += a[3] * c;
    }
    L += __shfl_xor(L, 16, 64);
    L += __shfl_xor(L, 32, 64);
    float inv = 1.f / L;
    int q = q0 + ql;
    int h = q / NW, wcol = q - h * NW;
    s16x4 ov;
    ov.x = f2bf(o[0] * inv);
    ov.y = f2bf(o[1] * inv);
    ov.z = f2bf(o[2] * inv);
    ov.w = f2bf(o[3] * inv);
    *(s16x4*)(aot + (((size_t)b * PH + h + 1) * PWS + wcol + 1) * 16 + g * 4) = ov;
  }
}

// ---------------- launch ----------------
extern "C" void kernel_launch(void* const* d_in, const int* in_sizes, int n_in,
                              void* d_out, int out_size, void* d_ws, size_t ws_size,
                              hipStream_t stream) {
  const float* x      = (const float*)d_in[0];
  const float* xe     = (const float*)d_in[1];
  const float* temb   = (const float*)d_in[2];
  const float* gn1w   = (const float*)d_in[3];
  const float* gn1b   = (const float*)d_in[4];
  const float* conv1w = (const float*)d_in[5];
  const float* conv1b = (const float*)d_in[6];
  const float* affw   = (const float*)d_in[7];
  const float* affb   = (const float*)d_in[8];
  const float* gn2w   = (const float*)d_in[9];
  const float* gn2b   = (const float*)d_in[10];
  const float* conv2w = (const float*)d_in[11];
  const float* conv2b = (const float*)d_in[12];
  const float* qw     = (const float*)d_in[13];
  const float* kvw    = (const float*)d_in[14];
  const float* outw   = (const float*)d_in[15];
  const float* outb   = (const float*)d_in[16];
  float* out = (float*)d_out;
  float* ws  = (float*)d_ws;

  // ws layout
  float* gbsum   = ws;                                   // 1,536
  float* gnpartA = gbsum + NB * NC;                      // 3,072
  float* gnpartB = gnpartA + 3072;                       // 512
  short* wbuf1   = (short*)(gnpartB + 512);                     // 331,776 bf16
  short* wbuf2   = wbuf1 + (size_t)6 * 9 * 12 * 64 * 8;         // 331,776 bf16
  short* wbufo   = wbuf2 + (size_t)6 * 9 * 12 * 64 * 8;         // 55,296 bf16
  short* awq     = wbufo + (size_t)9 * 12 * 64 * 8;             // 3,072 bf16
  short* awkv    = awq + 3072;                                  // 6,144 bf16
  short* actt    = awkv + 6144;                                 // 3,993,600 bf16
  short* Kb      = actt + ACT_T_ELEMS;                          // 589,824 bf16
  short* VTb     = Kb + (size_t)NB * NP * 32;                   // 294,912 bf16
  short* aot     = VTb + (size_t)NB * 16 * NP;                  // 332,800 bf16

  // 1. FRONT: all prep + gn1 stats + zero gnpartB
  front_kernel<<<4699, 256, 0, stream>>>(conv1w, conv2w, outw, qw, kvw, temb,
                                         affw, affb, x, wbuf1, wbuf2, wbufo, awq, awkv,
                                         gbsum, actt, aot, gnpartA, gnpartB);
  // 2. MID1: kv-projection(xe) + gn1-apply(x)
  mid1_kernel<<<768, 256, 0, stream>>>(xe, awkv, Kb, VTb, x, gnpartA, gn1w, gn1b, actt);
  // 3. conv1 + affine + fused gn2-stats
  conv_mfma_kernel<true, false, true><<<dim3(NB * 24, 3), 256, 0, stream>>>(
      actt, wbuf1, conv1b, gbsum, nullptr, out, gnpartB);
  // 4. gn2 apply
  gn_apply_raw_kernel<<<NB * NH, 256, 0, stream>>>(out, gnpartB, gn2w, gn2b, actt);
  // 5. conv2 + residual(x)
  conv_mfma_kernel<false, true, false><<<dim3(NB * 24, 3), 256, 0, stream>>>(
      actt, wbuf2, conv2b, nullptr, x, out, nullptr);
  // 6. attention with inline q-projection (reads xres = d_out)
  attn_mfma_kernel<<<dim3(36, NB), 1024, 0, stream>>>(out, awq, Kb, VTb, aot);
  // 7. out conv + residual (in-place on d_out)
  out_conv_mfma_kernel<<<dim3(NB * 24, 3), 256, 0, stream>>>(aot, wbufo, outb, out);
}